// Round 2
// baseline (102.766 us; speedup 1.0000x reference)
//
#include <hip/hip_runtime.h>

#define Bn 1024
#define Dn 512
#define Cn 512
#define Sn 4     // samples per block
#define NT 256   // threads per block

__device__ __forceinline__ float waveSum(float v) {
    #pragma unroll
    for (int off = 32; off > 0; off >>= 1) v += __shfl_xor(v, off, 64);
    return v;
}
__device__ __forceinline__ float waveMax(float v) {
    #pragma unroll
    for (int off = 32; off > 0; off >>= 1) v = fmaxf(v, __shfl_xor(v, off, 64));
    return v;
}

__global__ __launch_bounds__(NT) void gnorm_kernel(
    const float* __restrict__ x,     // [B, D]
    const float* __restrict__ y,     // [B, C]
    const float* __restrict__ W,     // [D, C]
    const float* __restrict__ bias,  // [C]
    float* __restrict__ out)         // [B]
{
    __shared__ float xs[Sn][Dn];     // 8 KB staged x rows
    __shared__ float rbuf[Sn][4];
    __shared__ float rbuf2[Sn][4];

    const int tid  = threadIdx.x;
    const int lane = tid & 63;
    const int wid  = tid >> 6;
    const int s0   = blockIdx.x * Sn;

    // Stage x rows into LDS; keep per-thread partial of ||x||^2.
    float xsqp[Sn];
    #pragma unroll
    for (int s = 0; s < Sn; ++s) {
        float v0 = x[(s0 + s) * Dn + tid];
        float v1 = x[(s0 + s) * Dn + tid + NT];
        xs[s][tid]      = v0;
        xs[s][tid + NT] = v1;
        xsqp[s] = v0 * v0 + v1 * v1;
    }
    __syncthreads();

    // Logits: each thread owns columns c0=tid, c1=tid+256 for all Sn samples.
    float acc0[Sn] = {0.f, 0.f, 0.f, 0.f};
    float acc1[Sn] = {0.f, 0.f, 0.f, 0.f};
    #pragma unroll 4
    for (int d = 0; d < Dn; ++d) {
        float w0 = W[d * Cn + tid];        // coalesced across lanes
        float w1 = W[d * Cn + tid + NT];
        #pragma unroll
        for (int s = 0; s < Sn; ++s) {
            float xv = xs[s][d];           // LDS broadcast (same addr all lanes)
            acc0[s] = fmaf(xv, w0, acc0[s]);
            acc1[s] = fmaf(xv, w1, acc1[s]);
        }
    }
    const float b0 = bias[tid], b1 = bias[tid + NT];
    float z0[Sn], z1[Sn];
    #pragma unroll
    for (int s = 0; s < Sn; ++s) { z0[s] = acc0[s] + b0; z1[s] = acc1[s] + b1; }

    // --- block max per sample ---
    #pragma unroll
    for (int s = 0; s < Sn; ++s) {
        float v = waveMax(fmaxf(z0[s], z1[s]));
        if (lane == 0) rbuf[s][wid] = v;
    }
    __syncthreads();
    float m[Sn];
    #pragma unroll
    for (int s = 0; s < Sn; ++s)
        m[s] = fmaxf(fmaxf(rbuf[s][0], rbuf[s][1]), fmaxf(rbuf[s][2], rbuf[s][3]));
    __syncthreads();

    // --- sum of exp ---
    float e0[Sn], e1[Sn];
    #pragma unroll
    for (int s = 0; s < Sn; ++s) {
        e0[s] = __expf(z0[s] - m[s]);
        e1[s] = __expf(z1[s] - m[s]);
        float v = waveSum(e0[s] + e1[s]);
        if (lane == 0) rbuf[s][wid] = v;
    }
    __syncthreads();
    float denom[Sn];
    #pragma unroll
    for (int s = 0; s < Sn; ++s)
        denom[s] = (rbuf[s][0] + rbuf[s][1]) + (rbuf[s][2] + rbuf[s][3]);
    __syncthreads();

    // --- ||g||^2 and ||x||^2 reductions ---
    #pragma unroll
    for (int s = 0; s < Sn; ++s) {
        float inv = 1.0f / denom[s];
        float g0 = e0[s] * inv - y[(s0 + s) * Cn + tid];
        float g1 = e1[s] * inv - y[(s0 + s) * Cn + tid + NT];
        float v  = waveSum(g0 * g0 + g1 * g1);
        if (lane == 0) rbuf[s][wid] = v;
        float v2 = waveSum(xsqp[s]);
        if (lane == 0) rbuf2[s][wid] = v2;
    }
    __syncthreads();

    if (tid < Sn) {
        int s = tid;
        float gsq = (rbuf[s][0] + rbuf[s][1]) + (rbuf[s][2] + rbuf[s][3]);
        float xn2 = (rbuf2[s][0] + rbuf2[s][1]) + (rbuf2[s][2] + rbuf2[s][3]);
        // ||gW||^2 + ||gb||^2 = (||x||^2 + 1) * ||g||^2
        out[s0 + s] = sqrtf((xn2 + 1.0f) * gsq);
    }
}

extern "C" void kernel_launch(void* const* d_in, const int* in_sizes, int n_in,
                              void* d_out, int out_size, void* d_ws, size_t ws_size,
                              hipStream_t stream) {
    const float* x  = (const float*)d_in[0];
    const float* y  = (const float*)d_in[1];
    const float* W  = (const float*)d_in[2];
    const float* b  = (const float*)d_in[3];
    float* out = (float*)d_out;
    gnorm_kernel<<<dim3(Bn / Sn), dim3(NT), 0, stream>>>(x, y, W, b, out);
}

// Round 3
// 78.791 us; speedup vs baseline: 1.3043x; 1.3043x over previous
//
#include <hip/hip_runtime.h>

#define Bn 1024
#define Dn 512
#define Cn 512
#define Sn 4      // samples per block (== number of d-quarters)
#define NT 1024   // threads per block -> 16 waves/CU = 4 waves/SIMD
#define DQ 128    // d-rows per quarter

__device__ __forceinline__ float waveSum(float v) {
    #pragma unroll
    for (int off = 32; off > 0; off >>= 1) v += __shfl_xor(v, off, 64);
    return v;
}
__device__ __forceinline__ float waveMax(float v) {
    #pragma unroll
    for (int off = 32; off > 0; off >>= 1) v = fmaxf(v, __shfl_xor(v, off, 64));
    return v;
}

__global__ __launch_bounds__(NT) void gnorm_kernel(
    const float* __restrict__ x,     // [B, D]
    const float* __restrict__ y,     // [B, C]
    const float* __restrict__ W,     // [D, C]
    const float* __restrict__ bias,  // [C]
    float* __restrict__ out)         // [B]
{
    __shared__ float xst[Dn][Sn];      // x transposed: xst[d][s], 8 KB, rows 16B-aligned
    __shared__ float zp[Sn][Sn][Cn];   // partial logits [quarter][sample][col], 32 KB
    __shared__ float rbuf[Sn][4];      // per-sample cross-wave reduce buffer
    __shared__ float xbuf[Sn][4];      // ||x||^2 partials

    const int tid  = threadIdx.x;
    const int q    = tid >> 8;         // d-quarter / sample owner, 0..3
    const int u    = tid & 255;        // col-pair index: cols 2u, 2u+1
    const int lane = tid & 63;
    const int w4   = (tid >> 6) & 3;   // wave index within quarter
    const int s0   = blockIdx.x * Sn;

    // ---- stage x transposed + ||x||^2 partials ----
    // flat element 2*tid within the block's 4 contiguous x rows: sample = tid>>8 = q
    float2 xv = *(const float2*)&x[(size_t)s0 * Dn + 2 * tid];
    const int o = (2 * tid) & 511;
    xst[o][q]     = xv.x;
    xst[o + 1][q] = xv.y;
    float xs_w = waveSum(xv.x * xv.x + xv.y * xv.y);   // partial of ||x_q||^2
    if (lane == 0) xbuf[q][w4] = xs_w;
    __syncthreads();

    // ---- partial logits: quarter q handles d in [q*DQ, q*DQ+DQ) ----
    const float2* Wp = (const float2*)W + (size_t)(q * DQ) * (Cn / 2) + u;
    float acc0[Sn] = {0.f, 0.f, 0.f, 0.f};
    float acc1[Sn] = {0.f, 0.f, 0.f, 0.f};
    #pragma unroll 8
    for (int dd = 0; dd < DQ; ++dd) {
        const int d = q * DQ + dd;
        float2 wv = Wp[(size_t)dd * (Cn / 2)];          // 8B/lane, 512B/wave contiguous
        float4 xq = *(const float4*)&xst[d][0];          // all 4 samples, same-addr broadcast
        acc0[0] = fmaf(xq.x, wv.x, acc0[0]); acc1[0] = fmaf(xq.x, wv.y, acc1[0]);
        acc0[1] = fmaf(xq.y, wv.x, acc0[1]); acc1[1] = fmaf(xq.y, wv.y, acc1[1]);
        acc0[2] = fmaf(xq.z, wv.x, acc0[2]); acc1[2] = fmaf(xq.z, wv.y, acc1[2]);
        acc0[3] = fmaf(xq.w, wv.x, acc0[3]); acc1[3] = fmaf(xq.w, wv.y, acc1[3]);
    }
    #pragma unroll
    for (int s = 0; s < Sn; ++s)
        *(float2*)&zp[q][s][2 * u] = make_float2(acc0[s], acc1[s]);
    __syncthreads();

    // ---- each quarter now owns ONE sample (sm = q): sum partials + bias ----
    float2 bv = *(const float2*)&bias[2 * u];
    float z0 = bv.x, z1 = bv.y;
    #pragma unroll
    for (int qq = 0; qq < Sn; ++qq) {
        float2 t = *(const float2*)&zp[qq][q][2 * u];
        z0 += t.x; z1 += t.y;
    }

    // ---- softmax max over the quarter's 4 waves ----
    float vmax = waveMax(fmaxf(z0, z1));
    if (lane == 0) rbuf[q][w4] = vmax;
    __syncthreads();
    float m = fmaxf(fmaxf(rbuf[q][0], rbuf[q][1]), fmaxf(rbuf[q][2], rbuf[q][3]));
    __syncthreads();

    // ---- sum of exp ----
    float e0 = __expf(z0 - m), e1 = __expf(z1 - m);
    float ssum = waveSum(e0 + e1);
    if (lane == 0) rbuf[q][w4] = ssum;
    __syncthreads();
    float denom = (rbuf[q][0] + rbuf[q][1]) + (rbuf[q][2] + rbuf[q][3]);
    __syncthreads();

    // ---- ||g||^2 ----
    float inv = 1.0f / denom;
    float2 yv = *(const float2*)&y[(size_t)(s0 + q) * Cn + 2 * u];
    float g0 = e0 * inv - yv.x;
    float g1 = e1 * inv - yv.y;
    float gs = waveSum(g0 * g0 + g1 * g1);
    if (lane == 0) rbuf[q][w4] = gs;
    __syncthreads();

    if (tid < Sn) {
        const int s = tid;
        float gsq = (rbuf[s][0] + rbuf[s][1]) + (rbuf[s][2] + rbuf[s][3]);
        float xn2 = (xbuf[s][0] + xbuf[s][1]) + (xbuf[s][2] + xbuf[s][3]);
        // ||gW||_F^2 + ||gb||^2 = (||x||^2 + 1) * ||g||^2
        out[s0 + s] = sqrtf((xn2 + 1.0f) * gsq);
    }
}

extern "C" void kernel_launch(void* const* d_in, const int* in_sizes, int n_in,
                              void* d_out, int out_size, void* d_ws, size_t ws_size,
                              hipStream_t stream) {
    const float* x  = (const float*)d_in[0];
    const float* y  = (const float*)d_in[1];
    const float* W  = (const float*)d_in[2];
    const float* b  = (const float*)d_in[3];
    float* out = (float*)d_out;
    gnorm_kernel<<<dim3(Bn / Sn), dim3(NT), 0, stream>>>(x, y, W, b, out);
}